// Round 16
// baseline (60.361 us; speedup 1.0000x reference)
//
#include <hip/hip_runtime.h>

#define Bn 8
#define Sn 8192
#define Dn 128
#define NCn 128

typedef _Float16 f16;
typedef f16 f16x2 __attribute__((ext_vector_type(2)));
typedef f16 f16x4 __attribute__((ext_vector_type(4)));
typedef float f32x4 __attribute__((ext_vector_type(4)));

static __device__ __forceinline__ f32x4 mfma16(f16x4 a, f16x4 b, f32x4 c) {
  return __builtin_amdgcn_mfma_f32_16x16x16f16(a, b, c, 0, 0, 0);
}

union UU { uint4 u; f16x2 h[4]; f16x4 q[2]; };

// Validated fragment conventions for mfma_f32_16x16x16f16 (rounds 0,2,3,4,6,7,9,10,13,15):
//   A-frag: lane l, reg j = A_op[l&15][4*(l>>4)+j]
//   B-frag: lane l, reg j = B_op[4*(l>>4)+j][l&15]
//   D-frag: lane l, reg j = D[4*(l>>4)+j][l&15]
//   D-frag of u == A-frag of u^T; packed D-frag [(r*8+c)*64+lane] == B-frag for
//   row-contraction; quarter mapping (gtile/slot <-> Mh4[(kk*2+tq)*64+lane])
//   validated rounds 9-15.
// Two-level scan split (r14/r15 validated):
//   Lf_seg = sum_t (prod_{r>t} d_r) Z_t ;  P_{seg-1} = sum_t wgt_t Lf_t
//   (descending wgt, wgt *= Df_t);  M init = P, then serial m-loop M = d*M + Z.
// XCD note: b = blk&7 everywhere so Z/Lf/x re-reads hit the writing XCD's L2.
// r16 change: xh buffer ELIMINATED — outfold reads f32 x directly (same f16
// rounding at LDS-stage time; bit-identical output).

// ---- precompute: 32 blocks x 4 waves (validated r13) ----
__global__ __launch_bounds__(256) void k_prep(
    const float* __restrict__ Wq, const float* __restrict__ Wk,
    const float* __restrict__ Wv, const float* __restrict__ Wout,
    f16* __restrict__ Amat, f16* __restrict__ r2) {
  const int blk = blockIdx.x;
  const int which = blk >> 4;
  const int w = threadIdx.x >> 6;
  const int t = (blk & 15) * 4 + w;
  const int ti = t >> 3, tj = t & 7;
  const int lane = threadIdx.x & 63, r16 = lane & 15, g4 = lane >> 4;
  f32x4 acc = {};
  if (which == 0) {  // Amat = Wq^T Wk
#pragma unroll
    for (int kk = 0; kk < 8; ++kk) {
      f16x4 af, bf;
#pragma unroll
      for (int j = 0; j < 4; ++j) {
        af[j] = (f16)Wq[(kk * 16 + g4 * 4 + j) * 128 + ti * 16 + r16];
        bf[j] = (f16)Wk[(kk * 16 + g4 * 4 + j) * 128 + tj * 16 + r16];
      }
      acc = mfma16(af, bf, acc);
    }
  } else {  // r2 = Wout Wv
#pragma unroll
    for (int kk = 0; kk < 8; ++kk) {
      f16x4 af, bf;
      float4 a4 = *(const float4*)(Wout + (ti * 16 + r16) * 128 + kk * 16 + g4 * 4);
      af[0] = (f16)a4.x; af[1] = (f16)a4.y; af[2] = (f16)a4.z; af[3] = (f16)a4.w;
#pragma unroll
      for (int j = 0; j < 4; ++j)
        bf[j] = (f16)Wv[(kk * 16 + g4 * 4 + j) * 128 + tj * 16 + r16];
      acc = mfma16(af, bf, acc);
    }
  }
  f16* dst = which ? r2 : Amat;
#pragma unroll
  for (int j = 0; j < 4; ++j)
    dst[(ti * 16 + g4 * 4 + j) * 128 + tj * 16 + r16] = (f16)acc[j];
}

// ---- fused: gate, u = x Amat^T, v = x r2^T, Z = (g.u)^T v ----
// Chunk-parallel (1024 blocks), validated r13/r15 body minus xh writes. b = h&7.
__global__ __launch_bounds__(512, 8) void k_phase1(
    const float* __restrict__ x, const float* __restrict__ gw, const float* __restrict__ gb,
    const f16* __restrict__ Amat, const f16* __restrict__ r2,
    f16x4* __restrict__ wtg, float* __restrict__ gavg) {
  __shared__ __align__(16) f16 Xs[64][136];
  __shared__ __align__(16) f16x4 vP[2048];
  __shared__ float gs[64];
  const int h = blockIdx.x;
  const int b = h & 7, seg = (h >> 3) & 15, m = h >> 7;
  const int c = seg * 8 + m;
  const int tid = threadIdx.x;
  {
    int s = tid >> 3, sub = tid & 7;
    const float* xrow = x + ((size_t)b * Sn + (size_t)c * 64 + s) * Dn;
    float gpart = 0.f;
#pragma unroll
    for (int i = 0; i < 4; ++i) {
      int col = sub * 4 + i * 32;
      float4 v = *(const float4*)(xrow + col);
      float4 g = *(const float4*)(gw + col);
      gpart += v.x * g.x + v.y * g.y + v.z * g.z + v.w * g.w;
      f16x4 hh = {(f16)v.x, (f16)v.y, (f16)v.z, (f16)v.w};
      *(f16x4*)&Xs[s][col] = hh;
    }
    gpart += __shfl_xor(gpart, 1);
    gpart += __shfl_xor(gpart, 2);
    gpart += __shfl_xor(gpart, 4);
    if (sub == 0) gs[s] = 1.f / (1.f + __expf(-(gpart + gb[0])));
  }
  __syncthreads();
  if (tid == 0) {
    float sum = 0.f;
#pragma unroll
    for (int i = 0; i < 64; ++i) sum += gs[i];
    gavg[b * NCn + c] = sum * (1.f / 64.f);
  }
  const int w = tid >> 6, lane = tid & 63, r16 = lane & 15, g4 = lane >> 4;
  f32x4 uacc[4] = {}, vacc[4] = {};
#pragma unroll
  for (int kk = 0; kk < 8; ++kk) {
    f16x4 bu = *(const f16x4*)&Amat[(w * 16 + r16) * 128 + kk * 16 + g4 * 4];
    f16x4 bv = *(const f16x4*)&r2[(w * 16 + r16) * 128 + kk * 16 + g4 * 4];
#pragma unroll
    for (int mr = 0; mr < 4; ++mr) {
      f16x4 af = *(f16x4*)&Xs[mr * 16 + r16][kk * 16 + g4 * 4];
      uacc[mr] = mfma16(af, bu, uacc[mr]);
      vacc[mr] = mfma16(af, bv, vacc[mr]);
    }
  }
  f16x4 ua[4];
#pragma unroll
  for (int mr = 0; mr < 4; ++mr) {
    float g0 = gs[mr * 16 + g4 * 4 + 0], g1 = gs[mr * 16 + g4 * 4 + 1];
    float g2 = gs[mr * 16 + g4 * 4 + 2], g3 = gs[mr * 16 + g4 * 4 + 3];
    f16x4 uh = {(f16)(uacc[mr][0] * g0), (f16)(uacc[mr][1] * g1),
                (f16)(uacc[mr][2] * g2), (f16)(uacc[mr][3] * g3)};
    ua[mr] = uh;
    f16x4 vh = {(f16)vacc[mr][0], (f16)vacc[mr][1], (f16)vacc[mr][2], (f16)vacc[mr][3]};
    vP[(mr * 8 + w) * 64 + lane] = vh;
  }
  __syncthreads();
  f32x4 z[8] = {};
#pragma unroll
  for (int ks = 0; ks < 4; ++ks)
#pragma unroll
    for (int ct = 0; ct < 8; ++ct)
      z[ct] = mfma16(ua[ks], vP[(ks * 8 + ct) * 64 + lane], z[ct]);
  f16x4* wdst = wtg + (size_t)(b * NCn + c) * 4096;
#pragma unroll
  for (int ct = 0; ct < 8; ++ct) {
    f16x4 zh = {(f16)z[ct][0], (f16)z[ct][1], (f16)z[ct][2], (f16)z[ct][3]};
    wdst[(w * 8 + ct) * 64 + lane] = zh;
  }
}

// ---- segsum: Lf_seg = sum_t (prod_{r>t} d_r) Z_t (validated r15) ----
__global__ __launch_bounds__(512) void k_segsum(
    const uint4* __restrict__ wtg4, const float* __restrict__ gavg,
    float4* __restrict__ Lf) {
  const int blk = blockIdx.x;
  const int b = blk & 7, q = (blk >> 3) & 3, seg = blk >> 5;
  const int tid = threadIdx.x;
  const int lt = tid >> 5;
  const int gtile = (lt >> 1) * 8 + q * 2 + (lt & 1);
  const int slot = tid & 31;

  float wt[8];
  wt[7] = 1.f;
#pragma unroll
  for (int t = 6; t >= 0; --t)
    wt[t] = wt[t + 1] * (1.f - gavg[b * NCn + seg * 8 + t + 1]);

  const uint4* Zseg = wtg4 + (size_t)(b * NCn + seg * 8) * 2048 + gtile * 32 + slot;
  float4 A0 = {0.f, 0.f, 0.f, 0.f}, A1 = {0.f, 0.f, 0.f, 0.f};
#pragma unroll
  for (int t = 0; t < 8; ++t) {
    UU z; z.u = Zseg[(size_t)t * 2048];
    float w = wt[t];
    A0.x += w * (float)z.h[0][0];
    A0.y += w * (float)z.h[0][1];
    A0.z += w * (float)z.h[1][0];
    A0.w += w * (float)z.h[1][1];
    A1.x += w * (float)z.h[2][0];
    A1.y += w * (float)z.h[2][1];
    A1.z += w * (float)z.h[3][0];
    A1.w += w * (float)z.h[3][1];
  }
  float4* lfd = Lf + (size_t)(b * 16 + seg) * 4096;
  const int f4i = gtile * 64 + slot * 2;
  lfd[f4i] = A0;
  lfd[f4i + 1] = A1;
}

// ---- outfold: P from Lf, then validated m-loop (reg-M, double-buffer, T14);
// r16: x read directly as f32, converted at LDS-stage (xh eliminated). ----
__global__ __launch_bounds__(512, 4) void k_outfold(
    const float* __restrict__ x, const uint4* __restrict__ wtg4,
    const float4* __restrict__ Lf, const float* __restrict__ gavg,
    float* __restrict__ outp) {
  __shared__ __align__(16) f16 Xs[2][64][136];   // 34816 B
  __shared__ __align__(16) f16x4 Mh4[2][1024];   // 16384 B
  const int blk = blockIdx.x;
  const int b = blk & 7, q = (blk >> 3) & 3, seg = blk >> 5;
  const int tid = threadIdx.x;
  const int w = tid >> 6, lane = tid & 63, r16 = lane & 15, g4 = lane >> 4;
  const int mr = w & 3, tq = w >> 2;
  const int lt = tid >> 5;
  const int gtile = (lt >> 1) * 8 + q * 2 + (lt & 1);
  const int slot = tid & 31;

  // ---- P_{seg-1} = sum_{t<seg} wgt_t Lf_t (validated descending fold) ----
  float4 M0 = {0.f, 0.f, 0.f, 0.f}, M1 = {0.f, 0.f, 0.f, 0.f};
  {
    const int f4i = gtile * 64 + slot * 2;
    float wgt = 1.f;
    for (int t = seg - 1; t >= 0; --t) {
      const float4* lp = Lf + (size_t)(b * 16 + t) * 4096;
      float4 a = lp[f4i], c4 = lp[f4i + 1];
      M0.x += wgt * a.x; M0.y += wgt * a.y; M0.z += wgt * a.z; M0.w += wgt * a.w;
      M1.x += wgt * c4.x; M1.y += wgt * c4.y; M1.z += wgt * c4.z; M1.w += wgt * c4.w;
      float df = 1.f;
#pragma unroll
      for (int i = 0; i < 8; ++i) df *= (1.f - gavg[b * NCn + t * 8 + i]);
      wgt *= df;
    }
  }

  float dseg[8];
#pragma unroll
  for (int t = 0; t < 8; ++t) dseg[t] = 1.f - gavg[b * NCn + seg * 8 + t];

  const uint4* Zseg = wtg4 + (size_t)(b * NCn + seg * 8) * 2048;
  const int xrow = tid >> 3, xcol = (tid & 7) * 16;
  const float* xbase = x + ((size_t)b * Sn + (size_t)seg * 512 + xrow) * Dn + xcol;

  // T14: preload chunk 0's x (f32) into regs
  float4 xr[4];
#pragma unroll
  for (int i = 0; i < 4; ++i) xr[i] = *(const float4*)(xbase + i * 4);

#pragma unroll
  for (int m = 0; m < 8; ++m) {
    f16(*Xsb)[136] = Xs[m & 1];
    f16x4* Mh = Mh4[m & 1];
    {  // convert staged x f32 -> f16, pack, 2x16B LDS stores
      UU pk;
#pragma unroll
      for (int i = 0; i < 4; ++i)
        pk.q[i & 1] = (i & 1) ? pk.q[1] : pk.q[0];  // placeholder to keep union live
#pragma unroll
      for (int i = 0; i < 2; ++i) {
        f16x4 h0 = {(f16)xr[2 * i].x, (f16)xr[2 * i].y, (f16)xr[2 * i].z, (f16)xr[2 * i].w};
        f16x4 h1 = {(f16)xr[2 * i + 1].x, (f16)xr[2 * i + 1].y, (f16)xr[2 * i + 1].z,
                    (f16)xr[2 * i + 1].w};
        UU o; o.q[0] = h0; o.q[1] = h1;
        *(uint4*)&Xsb[xrow][xcol + i * 8] = o.u;
      }
    }
    Mh[tid * 2] = (f16x4){(f16)M0.x, (f16)M0.y, (f16)M0.z, (f16)M0.w};
    Mh[tid * 2 + 1] = (f16x4){(f16)M1.x, (f16)M1.y, (f16)M1.z, (f16)M1.w};
    __syncthreads();  // this buffer visible; other buffer's reads long done

    UU z;  // early-issue this chunk's Z + next chunk's x (overlap with MFMAs)
    z.u = Zseg[(size_t)m * 2048 + gtile * 32 + slot];
    if (m < 7) {
      const float* xn = xbase + (size_t)(m + 1) * 64 * Dn;
#pragma unroll
      for (int i = 0; i < 4; ++i) xr[i] = *(const float4*)(xn + i * 4);
    }

    f32x4 acc = {};
#pragma unroll
    for (int kk = 0; kk < 8; ++kk) {
      f16x4 af = *(f16x4*)&Xsb[mr * 16 + r16][kk * 16 + g4 * 4];
      f16x4 bf = Mh[(kk * 2 + tq) * 64 + lane];
      acc = mfma16(af, bf, acc);
    }

    {  // M = d*M + Z (registers)
      float dd = dseg[m];
      M0.x = dd * M0.x + (float)z.h[0][0];
      M0.y = dd * M0.y + (float)z.h[0][1];
      M0.z = dd * M0.z + (float)z.h[1][0];
      M0.w = dd * M0.w + (float)z.h[1][1];
      M1.x = dd * M1.x + (float)z.h[2][0];
      M1.y = dd * M1.y + (float)z.h[2][1];
      M1.z = dd * M1.z + (float)z.h[3][0];
      M1.w = dd * M1.w + (float)z.h[3][1];
    }

    {  // store out tile (validated D-frag scatter)
      const int c = seg * 8 + m;
      float* ob = outp + ((size_t)b * Sn + (size_t)c * 64 + mr * 16 + g4 * 4) * Dn +
                  (q * 2 + tq) * 16 + r16;
#pragma unroll
      for (int j = 0; j < 4; ++j) ob[(size_t)j * Dn] = acc[j];
    }
    // no trailing barrier: next iteration uses the other Xs/Mh buffer
  }
}

extern "C" void kernel_launch(void* const* d_in, const int* in_sizes, int n_in,
                              void* d_out, int out_size, void* d_ws, size_t ws_size,
                              hipStream_t stream) {
  const float* x = (const float*)d_in[0];
  const float* Wq = (const float*)d_in[1];
  const float* Wk = (const float*)d_in[2];
  const float* Wv = (const float*)d_in[3];
  const float* gw = (const float*)d_in[4];
  const float* gb = (const float*)d_in[5];
  const float* Wout = (const float*)d_in[6];

  char* ws = (char*)d_ws;
  f16* Amat = (f16*)(ws + 0);                       // 32 KB
  f16* r2 = (f16*)(ws + 32768);                     // 32 KB
  float* gavg = (float*)(ws + 65536);               // 4 KB
  f16* wtg = (f16*)(ws + 69632);                    // 33.5 MB (Z, packed frags)
  float4* Lf = (float4*)(ws + 37556224);            // 8 MB (f32 segment sums)

  k_prep<<<dim3(32), dim3(256), 0, stream>>>(Wq, Wk, Wv, Wout, Amat, r2);
  k_phase1<<<dim3(Bn * NCn), dim3(512), 0, stream>>>(x, gw, gb, Amat, r2, (f16x4*)wtg,
                                                     gavg);
  k_segsum<<<dim3(512), dim3(512), 0, stream>>>((const uint4*)wtg, gavg, Lf);
  k_outfold<<<dim3(512), dim3(512), 0, stream>>>(x, (const uint4*)wtg, Lf, gavg,
                                                 (float*)d_out);
}

// Round 17
// 55.849 us; speedup vs baseline: 1.0808x; 1.0808x over previous
//
#include <hip/hip_runtime.h>

#define Bn 8
#define Sn 8192
#define Dn 128
#define NCn 128

typedef _Float16 f16;
typedef f16 f16x2 __attribute__((ext_vector_type(2)));
typedef f16 f16x4 __attribute__((ext_vector_type(4)));
typedef float f32x4 __attribute__((ext_vector_type(4)));

static __device__ __forceinline__ f32x4 mfma16(f16x4 a, f16x4 b, f32x4 c) {
  return __builtin_amdgcn_mfma_f32_16x16x16f16(a, b, c, 0, 0, 0);
}

union UU { uint4 u; f16x2 h[4]; f16x4 q[2]; };

// Validated fragment conventions for mfma_f32_16x16x16f16 (rounds 0,2,3,4,6,7,9,10,13,15):
//   A-frag: lane l, reg j = A_op[l&15][4*(l>>4)+j]
//   B-frag: lane l, reg j = B_op[4*(l>>4)+j][l&15]
//   D-frag: lane l, reg j = D[4*(l>>4)+j][l&15]
//   D-frag of u == A-frag of u^T; packed D-frag [(r*8+c)*64+lane] == B-frag for
//   row-contraction; quarter mapping (gtile/slot <-> Mh4[(kk*2+tq)*64+lane])
//   validated rounds 9-15.
// Two-level scan split (r14/r15 validated):
//   Lf_seg = sum_t (prod_{r>t} d_r) Z_t ;  P_{seg-1} = sum_t wgt_t Lf_t
//   (descending wgt, wgt *= Df_t);  M init = P, then serial m-loop M = d*M + Z.
// XCD note: b = blk&7 everywhere so Z/xh/Lf re-reads hit the writing XCD's L2.
// r17 = r15 verbatim (r16's xh-elimination regressed: moved bytes+convert into
// outfold's serial staging path; reverted).

// ---- precompute: 32 blocks x 4 waves (validated r13) ----
__global__ __launch_bounds__(256) void k_prep(
    const float* __restrict__ Wq, const float* __restrict__ Wk,
    const float* __restrict__ Wv, const float* __restrict__ Wout,
    f16* __restrict__ Amat, f16* __restrict__ r2) {
  const int blk = blockIdx.x;
  const int which = blk >> 4;
  const int w = threadIdx.x >> 6;
  const int t = (blk & 15) * 4 + w;
  const int ti = t >> 3, tj = t & 7;
  const int lane = threadIdx.x & 63, r16 = lane & 15, g4 = lane >> 4;
  f32x4 acc = {};
  if (which == 0) {  // Amat = Wq^T Wk
#pragma unroll
    for (int kk = 0; kk < 8; ++kk) {
      f16x4 af, bf;
#pragma unroll
      for (int j = 0; j < 4; ++j) {
        af[j] = (f16)Wq[(kk * 16 + g4 * 4 + j) * 128 + ti * 16 + r16];
        bf[j] = (f16)Wk[(kk * 16 + g4 * 4 + j) * 128 + tj * 16 + r16];
      }
      acc = mfma16(af, bf, acc);
    }
  } else {  // r2 = Wout Wv
#pragma unroll
    for (int kk = 0; kk < 8; ++kk) {
      f16x4 af, bf;
      float4 a4 = *(const float4*)(Wout + (ti * 16 + r16) * 128 + kk * 16 + g4 * 4);
      af[0] = (f16)a4.x; af[1] = (f16)a4.y; af[2] = (f16)a4.z; af[3] = (f16)a4.w;
#pragma unroll
      for (int j = 0; j < 4; ++j)
        bf[j] = (f16)Wv[(kk * 16 + g4 * 4 + j) * 128 + tj * 16 + r16];
      acc = mfma16(af, bf, acc);
    }
  }
  f16* dst = which ? r2 : Amat;
#pragma unroll
  for (int j = 0; j < 4; ++j)
    dst[(ti * 16 + g4 * 4 + j) * 128 + tj * 16 + r16] = (f16)acc[j];
}

// ---- fused: gate, u = x Amat^T, v = x r2^T, Z = (g.u)^T v + xh copy ----
// Chunk-parallel (1024 blocks), validated r13 body. b = h&7.
__global__ __launch_bounds__(512, 8) void k_phase1(
    const float* __restrict__ x, const float* __restrict__ gw, const float* __restrict__ gb,
    const f16* __restrict__ Amat, const f16* __restrict__ r2,
    f16x4* __restrict__ wtg, float* __restrict__ gavg, f16* __restrict__ xh) {
  __shared__ __align__(16) f16 Xs[64][136];
  __shared__ __align__(16) f16x4 vP[2048];
  __shared__ float gs[64];
  const int h = blockIdx.x;
  const int b = h & 7, seg = (h >> 3) & 15, m = h >> 7;
  const int c = seg * 8 + m;
  const int tid = threadIdx.x;
  {
    int s = tid >> 3, sub = tid & 7;
    const float* xrow = x + ((size_t)b * Sn + (size_t)c * 64 + s) * Dn;
    f16* xhrow = xh + (size_t)(b * NCn + c) * 8192 + s * 128;
    float gpart = 0.f;
#pragma unroll
    for (int i = 0; i < 4; ++i) {
      int col = sub * 4 + i * 32;
      float4 v = *(const float4*)(xrow + col);
      float4 g = *(const float4*)(gw + col);
      gpart += v.x * g.x + v.y * g.y + v.z * g.z + v.w * g.w;
      f16x4 hh = {(f16)v.x, (f16)v.y, (f16)v.z, (f16)v.w};
      *(f16x4*)&Xs[s][col] = hh;
      *(f16x4*)&xhrow[col] = hh;
    }
    gpart += __shfl_xor(gpart, 1);
    gpart += __shfl_xor(gpart, 2);
    gpart += __shfl_xor(gpart, 4);
    if (sub == 0) gs[s] = 1.f / (1.f + __expf(-(gpart + gb[0])));
  }
  __syncthreads();
  if (tid == 0) {
    float sum = 0.f;
#pragma unroll
    for (int i = 0; i < 64; ++i) sum += gs[i];
    gavg[b * NCn + c] = sum * (1.f / 64.f);
  }
  const int w = tid >> 6, lane = tid & 63, r16 = lane & 15, g4 = lane >> 4;
  f32x4 uacc[4] = {}, vacc[4] = {};
#pragma unroll
  for (int kk = 0; kk < 8; ++kk) {
    f16x4 bu = *(const f16x4*)&Amat[(w * 16 + r16) * 128 + kk * 16 + g4 * 4];
    f16x4 bv = *(const f16x4*)&r2[(w * 16 + r16) * 128 + kk * 16 + g4 * 4];
#pragma unroll
    for (int mr = 0; mr < 4; ++mr) {
      f16x4 af = *(f16x4*)&Xs[mr * 16 + r16][kk * 16 + g4 * 4];
      uacc[mr] = mfma16(af, bu, uacc[mr]);
      vacc[mr] = mfma16(af, bv, vacc[mr]);
    }
  }
  f16x4 ua[4];
#pragma unroll
  for (int mr = 0; mr < 4; ++mr) {
    float g0 = gs[mr * 16 + g4 * 4 + 0], g1 = gs[mr * 16 + g4 * 4 + 1];
    float g2 = gs[mr * 16 + g4 * 4 + 2], g3 = gs[mr * 16 + g4 * 4 + 3];
    f16x4 uh = {(f16)(uacc[mr][0] * g0), (f16)(uacc[mr][1] * g1),
                (f16)(uacc[mr][2] * g2), (f16)(uacc[mr][3] * g3)};
    ua[mr] = uh;
    f16x4 vh = {(f16)vacc[mr][0], (f16)vacc[mr][1], (f16)vacc[mr][2], (f16)vacc[mr][3]};
    vP[(mr * 8 + w) * 64 + lane] = vh;
  }
  __syncthreads();
  f32x4 z[8] = {};
#pragma unroll
  for (int ks = 0; ks < 4; ++ks)
#pragma unroll
    for (int ct = 0; ct < 8; ++ct)
      z[ct] = mfma16(ua[ks], vP[(ks * 8 + ct) * 64 + lane], z[ct]);
  f16x4* wdst = wtg + (size_t)(b * NCn + c) * 4096;
#pragma unroll
  for (int ct = 0; ct < 8; ++ct) {
    f16x4 zh = {(f16)z[ct][0], (f16)z[ct][1], (f16)z[ct][2], (f16)z[ct][3]};
    wdst[(w * 8 + ct) * 64 + lane] = zh;
  }
}

// ---- segsum: Lf_seg = sum_t (prod_{r>t} d_r) Z_t, per (b,seg,quarter). ----
__global__ __launch_bounds__(512) void k_segsum(
    const uint4* __restrict__ wtg4, const float* __restrict__ gavg,
    float4* __restrict__ Lf) {
  const int blk = blockIdx.x;
  const int b = blk & 7, q = (blk >> 3) & 3, seg = blk >> 5;
  const int tid = threadIdx.x;
  const int lt = tid >> 5;
  const int gtile = (lt >> 1) * 8 + q * 2 + (lt & 1);
  const int slot = tid & 31;

  float wt[8];
  wt[7] = 1.f;
#pragma unroll
  for (int t = 6; t >= 0; --t)
    wt[t] = wt[t + 1] * (1.f - gavg[b * NCn + seg * 8 + t + 1]);

  const uint4* Zseg = wtg4 + (size_t)(b * NCn + seg * 8) * 2048 + gtile * 32 + slot;
  float4 A0 = {0.f, 0.f, 0.f, 0.f}, A1 = {0.f, 0.f, 0.f, 0.f};
#pragma unroll
  for (int t = 0; t < 8; ++t) {
    UU z; z.u = Zseg[(size_t)t * 2048];
    float w = wt[t];
    A0.x += w * (float)z.h[0][0];
    A0.y += w * (float)z.h[0][1];
    A0.z += w * (float)z.h[1][0];
    A0.w += w * (float)z.h[1][1];
    A1.x += w * (float)z.h[2][0];
    A1.y += w * (float)z.h[2][1];
    A1.z += w * (float)z.h[3][0];
    A1.w += w * (float)z.h[3][1];
  }
  float4* lfd = Lf + (size_t)(b * 16 + seg) * 4096;
  const int f4i = gtile * 64 + slot * 2;
  lfd[f4i] = A0;
  lfd[f4i + 1] = A1;
}

// ---- outfold: P from Lf (<=15 iter), then validated m-loop (reg-M serial
// update, double-buffered Xs/Mh, T14 prefetch). ----
__global__ __launch_bounds__(512, 4) void k_outfold(
    const f16* __restrict__ xh, const uint4* __restrict__ wtg4,
    const float4* __restrict__ Lf, const float* __restrict__ gavg,
    float* __restrict__ outp) {
  __shared__ __align__(16) f16 Xs[2][64][136];   // 34816 B
  __shared__ __align__(16) f16x4 Mh4[2][1024];   // 16384 B
  const int blk = blockIdx.x;
  const int b = blk & 7, q = (blk >> 3) & 3, seg = blk >> 5;
  const int tid = threadIdx.x;
  const int w = tid >> 6, lane = tid & 63, r16 = lane & 15, g4 = lane >> 4;
  const int mr = w & 3, tq = w >> 2;
  const int lt = tid >> 5;
  const int gtile = (lt >> 1) * 8 + q * 2 + (lt & 1);
  const int slot = tid & 31;

  // ---- P_{seg-1} = sum_{t<seg} wgt_t Lf_t (validated descending fold) ----
  float4 M0 = {0.f, 0.f, 0.f, 0.f}, M1 = {0.f, 0.f, 0.f, 0.f};
  {
    const int f4i = gtile * 64 + slot * 2;
    float wgt = 1.f;
    for (int t = seg - 1; t >= 0; --t) {
      const float4* lp = Lf + (size_t)(b * 16 + t) * 4096;
      float4 a = lp[f4i], c4 = lp[f4i + 1];
      M0.x += wgt * a.x; M0.y += wgt * a.y; M0.z += wgt * a.z; M0.w += wgt * a.w;
      M1.x += wgt * c4.x; M1.y += wgt * c4.y; M1.z += wgt * c4.z; M1.w += wgt * c4.w;
      float df = 1.f;
#pragma unroll
      for (int i = 0; i < 8; ++i) df *= (1.f - gavg[b * NCn + t * 8 + i]);
      wgt *= df;
    }
  }

  float dseg[8];
#pragma unroll
  for (int t = 0; t < 8; ++t) dseg[t] = 1.f - gavg[b * NCn + seg * 8 + t];

  const uint4* Zseg = wtg4 + (size_t)(b * NCn + seg * 8) * 2048;
  const f16* xhseg = xh + (size_t)(b * NCn + seg * 8) * 8192;
  const int xrow = tid >> 3, xcol = (tid & 7) * 16;

  // T14: preload chunk 0's x into regs
  uint4 xa = ((const uint4*)xhseg)[tid * 2];
  uint4 xb2 = ((const uint4*)xhseg)[tid * 2 + 1];

#pragma unroll
  for (int m = 0; m < 8; ++m) {
    f16(*Xsb)[136] = Xs[m & 1];
    f16x4* Mh = Mh4[m & 1];
    *(uint4*)&Xsb[xrow][xcol] = xa;
    *(uint4*)&Xsb[xrow][xcol + 8] = xb2;
    Mh[tid * 2] = (f16x4){(f16)M0.x, (f16)M0.y, (f16)M0.z, (f16)M0.w};
    Mh[tid * 2 + 1] = (f16x4){(f16)M1.x, (f16)M1.y, (f16)M1.z, (f16)M1.w};
    __syncthreads();  // this buffer visible; other buffer's reads long done

    UU z;  // early-issue this chunk's Z + next chunk's x (overlap with MFMAs)
    z.u = Zseg[(size_t)m * 2048 + gtile * 32 + slot];
    if (m < 7) {
      const uint4* xn = (const uint4*)(xhseg + (size_t)(m + 1) * 8192);
      xa = xn[tid * 2];
      xb2 = xn[tid * 2 + 1];
    }

    f32x4 acc = {};
#pragma unroll
    for (int kk = 0; kk < 8; ++kk) {
      f16x4 af = *(f16x4*)&Xsb[mr * 16 + r16][kk * 16 + g4 * 4];
      f16x4 bf = Mh[(kk * 2 + tq) * 64 + lane];
      acc = mfma16(af, bf, acc);
    }

    {  // M = d*M + Z (registers)
      float dd = dseg[m];
      M0.x = dd * M0.x + (float)z.h[0][0];
      M0.y = dd * M0.y + (float)z.h[0][1];
      M0.z = dd * M0.z + (float)z.h[1][0];
      M0.w = dd * M0.w + (float)z.h[1][1];
      M1.x = dd * M1.x + (float)z.h[2][0];
      M1.y = dd * M1.y + (float)z.h[2][1];
      M1.z = dd * M1.z + (float)z.h[3][0];
      M1.w = dd * M1.w + (float)z.h[3][1];
    }

    {  // store out tile (validated D-frag scatter)
      const int c = seg * 8 + m;
      float* ob = outp + ((size_t)b * Sn + (size_t)c * 64 + mr * 16 + g4 * 4) * Dn +
                  (q * 2 + tq) * 16 + r16;
#pragma unroll
      for (int j = 0; j < 4; ++j) ob[(size_t)j * Dn] = acc[j];
    }
    // no trailing barrier: next iteration uses the other Xs/Mh buffer
  }
}

extern "C" void kernel_launch(void* const* d_in, const int* in_sizes, int n_in,
                              void* d_out, int out_size, void* d_ws, size_t ws_size,
                              hipStream_t stream) {
  const float* x = (const float*)d_in[0];
  const float* Wq = (const float*)d_in[1];
  const float* Wk = (const float*)d_in[2];
  const float* Wv = (const float*)d_in[3];
  const float* gw = (const float*)d_in[4];
  const float* gb = (const float*)d_in[5];
  const float* Wout = (const float*)d_in[6];

  char* ws = (char*)d_ws;
  f16* Amat = (f16*)(ws + 0);                       // 32 KB
  f16* r2 = (f16*)(ws + 32768);                     // 32 KB
  float* gavg = (float*)(ws + 65536);               // 4 KB
  f16* wtg = (f16*)(ws + 69632);                    // 33.5 MB (Z, packed frags)
  f16* xh = (f16*)(ws + 37556224);                  // 16.8 MB (x in f16)
  float4* Lf = (float4*)(ws + 54333440);            // 8 MB (f32 segment sums)

  k_prep<<<dim3(32), dim3(256), 0, stream>>>(Wq, Wk, Wv, Wout, Amat, r2);
  k_phase1<<<dim3(Bn * NCn), dim3(512), 0, stream>>>(x, gw, gb, Amat, r2, (f16x4*)wtg,
                                                     gavg, xh);
  k_segsum<<<dim3(512), dim3(512), 0, stream>>>((const uint4*)wtg, gavg, Lf);
  k_outfold<<<dim3(512), dim3(512), 0, stream>>>(xh, (const uint4*)wtg, Lf, gavg,
                                                 (float*)d_out);
}